// Round 8
// baseline (202.690 us; speedup 1.0000x reference)
//
#include <hip/hip_runtime.h>

// LDPC neural BP decoder, MI355X. Round 8.
// R7 (130 us): 2 rows/block, b64 pair-gathers, unroll-1 phase 2. Counters:
// LDS pipe ~54% of cycles, VALUBusy 72% (gfx94x-formula, possibly inflated).
// R6->R7 showed remaining VALU is per-row work. This round cuts VALU issue:
//  (1) packed dual-f32 (v_pk_mul/fma/max_f32) on 2-row vectors -- product
//      tree 20->9 instrs, clips 8->4, updates ~10->4;
//  (2) LDS byte offsets (idx*8) precomputed once per call into d_ws (indices
//      are iteration-invariant; saves 10 lshl per pair-node-iter).
// Doubles as a probe: no speedup => VALUBusy inflated, LDS/stall-bound,
// next round restructures. Phase 2 stays #pragma unroll 1 (R6: spill guard).

#define NN    8448
#define MAXNB 10
#define TPB   1024
#define MAXK  9       // ceil(8448/1024); k=8 active only for tid<256
#define ITERS 5
#define LDS_BYTES (NN * 2 * (int)sizeof(float))        // 67584
#define OFFS_BYTES ((size_t)NN * MAXNB * sizeof(int))  // 337920

typedef float v2f __attribute__((ext_vector_type(2)));

__global__ __launch_bounds__(256)
void prep_offsets_kernel(const int* __restrict__ cidx, int* __restrict__ offs)
{
    int i = blockIdx.x * 256 + threadIdx.x;
    if (i < NN * MAXNB) offs[i] = cidx[i] * 8;   // byte offset of float2 in LDS
}

template<bool USE_OFF>
__global__ __launch_bounds__(TPB)
void ldpc_decode_kernel(const float* __restrict__ input_llr,
                        const float* __restrict__ w_ch,
                        const float* __restrict__ w_res,   // [2][NN]
                        const int*   __restrict__ cidx,    // [NN][10]
                        const int*   __restrict__ offs,    // [NN][10] byte offs
                        float* __restrict__ out)
{
    extern __shared__ v2f t2[];          // [NN], interleaved rows {r0, r1}
    const int tid  = threadIdx.x;
    const int row0 = blockIdx.x * 2;
    const float* __restrict__ in0 = input_llr + (size_t)row0 * NN;
    const float* __restrict__ in1 = in0 + NN;
    float* __restrict__ out0 = out + (size_t)row0 * NN;
    float* __restrict__ out1 = out0 + NN;
    const char* __restrict__ smbase = (const char*)t2;

    // persistent state: vm/vmp pairs for both rows (36 VGPRs)
    v2f vm[MAXK], vmp[MAXK];

    // prologue: vm = input * w_ch; prev = 0
    #pragma unroll
    for (int k = 0; k < MAXK; ++k) {
        int n = tid + k * TPB;
        vmp[k] = (v2f)(0.0f);
        vm[k]  = (v2f)(0.0f);
        if (k < MAXK - 1 || n < NN) {
            float wc = w_ch[n];
            v2f x; x.x = in0[n]; x.y = in1[n];
            vm[k] = x * wc;                       // pk_mul
        }
    }

    for (int it = 0; it < ITERS; ++it) {
        // phase 1: t = tanh(clip(0.5*vm, +-9.9)) = 1 - 2/(exp(clip(vm,+-19.8))+1)
        #pragma unroll
        for (int k = 0; k < MAXK; ++k) {
            int n = tid + k * TPB;
            if (k < MAXK - 1 || n < NN) {
                v2f y = __builtin_elementwise_min(
                            __builtin_elementwise_max(vm[k], (v2f)(-19.8f)),
                            (v2f)(19.8f));
                v2f t;
                t.x = 1.0f - __fdividef(2.0f, __expf(y.x) + 1.0f);
                t.y = 1.0f - __fdividef(2.0f, __expf(y.y) + 1.0f);
                t2[n] = t;                        // ds_write_b64, stride-1
            }
        }
        __syncthreads();

        // phase 2: 10 b64 gathers serve both rows; packed-f32 arithmetic
        #pragma unroll 1
        for (int k = 0; k < MAXK; ++k) {
            int n = tid + k * TPB;
            if (n < NN) {
                v2f a0, b0, a1, b1, a2, b2, a3, b3, a4, b4;
                if (USE_OFF) {
                    const int2* op = (const int2*)(offs + n * MAXNB);
                    int2 o0 = op[0], o1 = op[1], o2 = op[2], o3 = op[3], o4 = op[4];
                    a0 = *(const v2f*)(smbase + o0.x); b0 = *(const v2f*)(smbase + o0.y);
                    a1 = *(const v2f*)(smbase + o1.x); b1 = *(const v2f*)(smbase + o1.y);
                    a2 = *(const v2f*)(smbase + o2.x); b2 = *(const v2f*)(smbase + o2.y);
                    a3 = *(const v2f*)(smbase + o3.x); b3 = *(const v2f*)(smbase + o3.y);
                    a4 = *(const v2f*)(smbase + o4.x); b4 = *(const v2f*)(smbase + o4.y);
                } else {
                    const int2* ip = (const int2*)(cidx + n * MAXNB);
                    int2 i0 = ip[0], i1 = ip[1], i2 = ip[2], i3 = ip[3], i4 = ip[4];
                    a0 = t2[i0.x]; b0 = t2[i0.y];
                    a1 = t2[i1.x]; b1 = t2[i1.y];
                    a2 = t2[i2.x]; b2 = t2[i2.y];
                    a3 = t2[i3.x]; b3 = t2[i3.y];
                    a4 = t2[i4.x]; b4 = t2[i4.y];
                }
                // product tree: 9 pk_muls
                v2f m01 = (a0 * b0) * (a1 * b1);
                v2f m23 = (a2 * b2) * (a3 * b3);
                v2f pr  = (m01 * m23) * (a4 * b4);
                pr = __builtin_elementwise_min(
                         __builtin_elementwise_max(pr, (v2f)(-0.999999f)),
                         (v2f)(0.999999f));
                // check = ln((1+pr)/(1-pr)); logs/rcp scalar (no pk form)
                v2f num = 1.0f + pr;
                v2f den = 1.0f - pr;
                v2f check;
                check.x = __logf(__fdividef(num.x, den.x));
                check.y = __logf(__fdividef(num.y, den.y));
                float wc  = w_ch[n];               // L2 hit
                float wr0 = w_res[n];              // L2 hit
                float wr1 = w_res[NN + n];         // L2 hit
                v2f x; x.x = in0[n]; x.y = in1[n];
                v2f nv = x * wc + check + wr0 * vm[k] + wr1 * vmp[k];  // pk chain
                vmp[k] = vm[k];
                vm[k]  = nv;
            }
        }
        __syncthreads();
    }

    // epilogue: sigmoid(vm + input)
    #pragma unroll
    for (int k = 0; k < MAXK; ++k) {
        int n = tid + k * TPB;
        if (k < MAXK - 1 || n < NN) {
            float x0 = vm[k].x + in0[n];
            float x1 = vm[k].y + in1[n];
            out0[n] = __fdividef(1.0f, 1.0f + __expf(-x0));
            out1[n] = __fdividef(1.0f, 1.0f + __expf(-x1));
        }
    }
}

extern "C" void kernel_launch(void* const* d_in, const int* in_sizes, int n_in,
                              void* d_out, int out_size, void* d_ws, size_t ws_size,
                              hipStream_t stream) {
    const float* input_llr = (const float*)d_in[0];
    const float* w_ch      = (const float*)d_in[1];
    const float* w_res     = (const float*)d_in[2];
    const int*   cidx      = (const int*)d_in[3];
    // d_in[4] (var_index_tensor) is unused by the reference
    float* out = (float*)d_out;
    int batch = in_sizes[0] / NN;
    const bool use_off = (ws_size >= OFFS_BYTES) && (d_ws != nullptr);

    hipFuncSetAttribute((const void*)ldpc_decode_kernel<true>,
                        hipFuncAttributeMaxDynamicSharedMemorySize, LDS_BYTES);
    hipFuncSetAttribute((const void*)ldpc_decode_kernel<false>,
                        hipFuncAttributeMaxDynamicSharedMemorySize, LDS_BYTES);

    if (use_off) {
        int* offs = (int*)d_ws;
        hipLaunchKernelGGL(prep_offsets_kernel, dim3((NN * MAXNB + 255) / 256),
                           dim3(256), 0, stream, cidx, offs);
        hipLaunchKernelGGL(ldpc_decode_kernel<true>, dim3(batch / 2), dim3(TPB),
                           LDS_BYTES, stream, input_llr, w_ch, w_res, cidx, offs, out);
    } else {
        hipLaunchKernelGGL(ldpc_decode_kernel<false>, dim3(batch / 2), dim3(TPB),
                           LDS_BYTES, stream, input_llr, w_ch, w_res, cidx, nullptr, out);
    }
}

// Round 9
// 196.506 us; speedup vs baseline: 1.0315x; 1.0315x over previous
//
#include <hip/hip_runtime.h>

// LDPC neural BP decoder, MI355X. Round 9.
// R8 probe: cutting VALU issue 30% didn't help (135 vs 130 us) -> not
// VALU-bound; pk-math spilled (alignment pressure) -> reverted to scalar.
// Model: LDS pipe ~65 us demand but only ~50% utilized -- every k-step
// starts with a ~300-cyc L2 wait for indices, waves aligned by the barrier.
// Fix: software-pipeline the offset loads: prefetch k+1's byte offsets
// (10 regs) during k's gathers/compute; last step wraps to tid so the regs
// roll into the next iteration's k=0 (offset latency also hidden under
// barrier + phase 1). Offs table (cidx*8) precomputed in d_ws (kept from R8).
// Phase 2 stays #pragma unroll 1 (R6: full unroll = spill).

#define NN    8448
#define MAXNB 10
#define TPB   1024
#define MAXK  9       // ceil(8448/1024); at k=8 waves with tid>=256 are fully inactive
#define ITERS 5
#define LDS_BYTES (NN * 2 * (int)sizeof(float))        // 67584
#define OFFS_BYTES ((size_t)NN * MAXNB * sizeof(int))  // 337920

__global__ __launch_bounds__(256)
void prep_offsets_kernel(const int* __restrict__ cidx, int* __restrict__ offs)
{
    int i = blockIdx.x * 256 + threadIdx.x;
    if (i < NN * MAXNB) offs[i] = cidx[i] * 8;   // byte offset of float2 in LDS
}

template<bool USE_OFF>
__device__ __forceinline__ int2 load_off(const int* __restrict__ tab, int n, int j)
{
    int2 v = ((const int2*)(tab + n * MAXNB))[j];
    if (!USE_OFF) { v.x <<= 3; v.y <<= 3; }      // cidx fallback: *8 on the fly
    return v;
}

template<bool USE_OFF>
__global__ __launch_bounds__(TPB)
void ldpc_decode_kernel(const float* __restrict__ input_llr,
                        const float* __restrict__ w_ch,
                        const float* __restrict__ w_res,   // [2][NN]
                        const int*   __restrict__ tab,     // offs (bytes) or cidx
                        float* __restrict__ out)
{
    extern __shared__ char smem[];
    float2* __restrict__ t2 = (float2*)smem;     // [NN] interleaved rows {r0,r1}
    const char* __restrict__ smbase = smem;
    const int tid  = threadIdx.x;
    const int row0 = blockIdx.x * 2;
    const float* __restrict__ in0 = input_llr + (size_t)row0 * NN;
    const float* __restrict__ in1 = in0 + NN;
    float* __restrict__ out0 = out + (size_t)row0 * NN;
    float* __restrict__ out1 = out0 + NN;

    // persistent state: vm/vmp for both rows (36 VGPRs)
    float vm0[MAXK], vm1[MAXK], vmp0[MAXK], vmp1[MAXK];

    // prologue: vm = input * w_ch; prev = 0
    #pragma unroll
    for (int k = 0; k < MAXK; ++k) {
        int n = tid + k * TPB;
        vmp0[k] = 0.0f; vmp1[k] = 0.0f;
        vm0[k] = 0.0f;  vm1[k] = 0.0f;
        if (k < MAXK - 1 || n < NN) {
            float wc = w_ch[n];
            vm0[k] = in0[n] * wc;
            vm1[k] = in1[n] * wc;
        }
    }

    // pipeline prime: offsets for k=0 (n = tid)
    int2 o0 = load_off<USE_OFF>(tab, tid, 0);
    int2 o1 = load_off<USE_OFF>(tab, tid, 1);
    int2 o2 = load_off<USE_OFF>(tab, tid, 2);
    int2 o3 = load_off<USE_OFF>(tab, tid, 3);
    int2 o4 = load_off<USE_OFF>(tab, tid, 4);

    for (int it = 0; it < ITERS; ++it) {
        // phase 1: t = tanh(clip(0.5*vm, +-9.9)) = 1 - 2/(exp(clip(vm,+-19.8))+1)
        #pragma unroll
        for (int k = 0; k < MAXK; ++k) {
            int n = tid + k * TPB;
            if (k < MAXK - 1 || n < NN) {
                float y0 = fminf(fmaxf(vm0[k], -19.8f), 19.8f);
                float y1 = fminf(fmaxf(vm1[k], -19.8f), 19.8f);
                float t0 = 1.0f - __fdividef(2.0f, __expf(y0) + 1.0f);
                float t1 = 1.0f - __fdividef(2.0f, __expf(y1) + 1.0f);
                t2[n] = make_float2(t0, t1);     // ds_write_b64, stride-1
            }
        }
        __syncthreads();

        // phase 2: pipelined -- prefetch k+1 offsets during k's gather/compute.
        // Wrap target: last valid step prefetches n=tid, priming next iteration.
        #pragma unroll 1
        for (int k = 0; k < MAXK; ++k) {
            int n = tid + k * TPB;
            if (n < NN) {
                // (1) prefetch next offsets (wrap to tid when past the end)
                int np = n + TPB; np = (np < NN) ? np : tid;
                int2 q0 = load_off<USE_OFF>(tab, np, 0);
                int2 q1 = load_off<USE_OFF>(tab, np, 1);
                int2 q2 = load_off<USE_OFF>(tab, np, 2);
                int2 q3 = load_off<USE_OFF>(tab, np, 3);
                int2 q4 = load_off<USE_OFF>(tab, np, 4);
                // (2) weights/inputs for the tail (issue early, needed late)
                float wc  = w_ch[n];
                float wr0 = w_res[n];
                float wr1 = w_res[NN + n];
                float x0  = in0[n];
                float x1  = in1[n];
                // (3) gathers from current offsets (10x ds_read_b64)
                float2 a0 = *(const float2*)(smbase + o0.x);
                float2 b0 = *(const float2*)(smbase + o0.y);
                float2 a1 = *(const float2*)(smbase + o1.x);
                float2 b1 = *(const float2*)(smbase + o1.y);
                float2 a2 = *(const float2*)(smbase + o2.x);
                float2 b2 = *(const float2*)(smbase + o2.y);
                float2 a3 = *(const float2*)(smbase + o3.x);
                float2 b3 = *(const float2*)(smbase + o3.y);
                float2 a4 = *(const float2*)(smbase + o4.x);
                float2 b4 = *(const float2*)(smbase + o4.y);
                // (4) product trees, clip, check (scalar per row)
                float pr0 = ((a0.x*b0.x)*(a1.x*b1.x)) * ((a2.x*b2.x)*(a3.x*b3.x)) * (a4.x*b4.x);
                float pr1 = ((a0.y*b0.y)*(a1.y*b1.y)) * ((a2.y*b2.y)*(a3.y*b3.y)) * (a4.y*b4.y);
                pr0 = fminf(fmaxf(pr0, -0.999999f), 0.999999f);
                pr1 = fminf(fmaxf(pr1, -0.999999f), 0.999999f);
                float check0 = __logf(__fdividef(1.0f + pr0, 1.0f - pr0));
                float check1 = __logf(__fdividef(1.0f + pr1, 1.0f - pr1));
                // (5) residual update
                float nv0 = x0 * wc + check0 + wr0 * vm0[k] + wr1 * vmp0[k];
                float nv1 = x1 * wc + check1 + wr0 * vm1[k] + wr1 * vmp1[k];
                vmp0[k] = vm0[k]; vm0[k] = nv0;
                vmp1[k] = vm1[k]; vm1[k] = nv1;
                // (6) rotate pipeline regs
                o0 = q0; o1 = q1; o2 = q2; o3 = q3; o4 = q4;
            }
        }
        __syncthreads();
    }

    // epilogue: sigmoid(vm + input)
    #pragma unroll
    for (int k = 0; k < MAXK; ++k) {
        int n = tid + k * TPB;
        if (k < MAXK - 1 || n < NN) {
            float x0 = vm0[k] + in0[n];
            float x1 = vm1[k] + in1[n];
            out0[n] = __fdividef(1.0f, 1.0f + __expf(-x0));
            out1[n] = __fdividef(1.0f, 1.0f + __expf(-x1));
        }
    }
}

extern "C" void kernel_launch(void* const* d_in, const int* in_sizes, int n_in,
                              void* d_out, int out_size, void* d_ws, size_t ws_size,
                              hipStream_t stream) {
    const float* input_llr = (const float*)d_in[0];
    const float* w_ch      = (const float*)d_in[1];
    const float* w_res     = (const float*)d_in[2];
    const int*   cidx      = (const int*)d_in[3];
    // d_in[4] (var_index_tensor) is unused by the reference
    float* out = (float*)d_out;
    int batch = in_sizes[0] / NN;
    const bool use_off = (ws_size >= OFFS_BYTES) && (d_ws != nullptr);

    hipFuncSetAttribute((const void*)ldpc_decode_kernel<true>,
                        hipFuncAttributeMaxDynamicSharedMemorySize, LDS_BYTES);
    hipFuncSetAttribute((const void*)ldpc_decode_kernel<false>,
                        hipFuncAttributeMaxDynamicSharedMemorySize, LDS_BYTES);

    if (use_off) {
        int* offs = (int*)d_ws;
        hipLaunchKernelGGL(prep_offsets_kernel, dim3((NN * MAXNB + 255) / 256),
                           dim3(256), 0, stream, cidx, offs);
        hipLaunchKernelGGL(ldpc_decode_kernel<true>, dim3(batch / 2), dim3(TPB),
                           LDS_BYTES, stream, input_llr, w_ch, w_res, offs, out);
    } else {
        hipLaunchKernelGGL(ldpc_decode_kernel<false>, dim3(batch / 2), dim3(TPB),
                           LDS_BYTES, stream, input_llr, w_ch, w_res, cidx, out);
    }
}

// Round 10
// 160.264 us; speedup vs baseline: 1.2647x; 1.2261x over previous
//
#include <hip/hip_runtime.h>

// LDPC neural BP decoder, MI355X. Round 10.
// Cross-round: VALU busy-cycles invariant ~240 K cyc/CU (R6-R9) and now 78%
// busy -> VALU-issue-bound. R8's pk loss was spill (persistent v2f arrays),
// not pk itself. This round cuts VALU issue pressure-neutrally:
//  - drop R9 prefetch/rotate (neutral, -10 movs, -10 regs)
//  - pk-f32 on gathered LDS pairs only (tree 18->9, clip 4->2); vm/vmp scalar
//  - check = (log2(1+p)-log2(1-p))*ln2  (no rcp)
//  - phase-1 shared rcp for both rows
//  - d_ws: offs padded 12/row (2x int4 + int2) + packed {wc,wr0,wr1} float4
// Phase 2 stays #pragma unroll 1 (R6: full unroll = spill).

#define NN    8448
#define MAXNB 10
#define TPB   1024
#define MAXK  9       // ceil(8448/1024)
#define ITERS 5
#define LDS_BYTES  (NN * 2 * (int)sizeof(float))          // 67584
#define OFFS_INTS  12                                     // padded row stride
#define OFFS_BYTES ((size_t)NN * OFFS_INTS * sizeof(int)) // 405504 (16-aligned)
#define W4_BYTES   ((size_t)NN * 4 * sizeof(float))       // 135168
#define WS_NEEDED  (OFFS_BYTES + W4_BYTES)                // 540672

typedef float v2f __attribute__((ext_vector_type(2)));

__global__ __launch_bounds__(256)
void prep_kernel(const int* __restrict__ cidx, const float* __restrict__ w_ch,
                 const float* __restrict__ w_res, int* __restrict__ offs,
                 float4* __restrict__ w4)
{
    int n = blockIdx.x * 256 + threadIdx.x;
    if (n < NN) {
        #pragma unroll
        for (int j = 0; j < MAXNB; ++j)
            offs[n * OFFS_INTS + j] = cidx[n * MAXNB + j] * 8;  // byte off of float2
        offs[n * OFFS_INTS + 10] = 0;
        offs[n * OFFS_INTS + 11] = 0;
        w4[n] = make_float4(w_ch[n], w_res[n], w_res[NN + n], 0.0f);
    }
}

template<bool USE_OFF>
__global__ __launch_bounds__(TPB)
void ldpc_decode_kernel(const float* __restrict__ input_llr,
                        const float* __restrict__ w_ch,
                        const float* __restrict__ w_res,   // [2][NN]
                        const int*   __restrict__ cidx,    // [NN][10]
                        const int*   __restrict__ offs,    // [NN][12] byte offs
                        const float4* __restrict__ w4,     // [NN] {wc,wr0,wr1,-}
                        float* __restrict__ out)
{
    extern __shared__ char smem[];
    v2f* __restrict__ t2 = (v2f*)smem;           // [NN] interleaved {r0,r1}
    const char* __restrict__ smbase = smem;
    const int tid  = threadIdx.x;
    const int row0 = blockIdx.x * 2;
    const float* __restrict__ in0 = input_llr + (size_t)row0 * NN;
    const float* __restrict__ in1 = in0 + NN;
    float* __restrict__ out0 = out + (size_t)row0 * NN;
    float* __restrict__ out1 = out0 + NN;

    // persistent state: vm/vmp for both rows, SCALAR arrays (36 VGPRs)
    float vm0[MAXK], vm1[MAXK], vmp0[MAXK], vmp1[MAXK];

    #pragma unroll
    for (int k = 0; k < MAXK; ++k) {
        int n = tid + k * TPB;
        vmp0[k] = 0.0f; vmp1[k] = 0.0f;
        vm0[k] = 0.0f;  vm1[k] = 0.0f;
        if (k < MAXK - 1 || n < NN) {
            float wc = w_ch[n];
            vm0[k] = in0[n] * wc;
            vm1[k] = in1[n] * wc;
        }
    }

    for (int it = 0; it < ITERS; ++it) {
        // phase 1: t = tanh(clip(0.5*vm,+-9.9)) = 1 - 2/(exp(clip(vm,+-19.8))+1)
        // shared reciprocal: r = rcp(A*B); 1/A = r*B; 1/B = r*A
        #pragma unroll
        for (int k = 0; k < MAXK; ++k) {
            int n = tid + k * TPB;
            if (k < MAXK - 1 || n < NN) {
                float y0 = fminf(fmaxf(vm0[k], -19.8f), 19.8f);
                float y1 = fminf(fmaxf(vm1[k], -19.8f), 19.8f);
                float A = __expf(y0) + 1.0f;
                float B = __expf(y1) + 1.0f;
                float r = __builtin_amdgcn_rcpf(A * B);
                v2f t;
                t.x = fmaf(r * B, -2.0f, 1.0f);
                t.y = fmaf(r * A, -2.0f, 1.0f);
                t2[n] = t;                               // ds_write_b64
            }
        }
        __syncthreads();

        // phase 2: 10 b64 pair-gathers; pk product tree; log-difference check
        #pragma unroll 1
        for (int k = 0; k < MAXK; ++k) {
            int n = tid + k * TPB;
            if (n < NN) {
                int oa0, oa1, oa2, oa3, oa4, ob0, ob1, ob2, ob3, ob4;
                if (USE_OFF) {
                    const int4* op = (const int4*)(offs + n * OFFS_INTS);
                    int4 oA = op[0];                     // 16-aligned
                    int4 oB = op[1];
                    int2 oC = ((const int2*)op)[4];
                    oa0 = oA.x; ob0 = oA.y; oa1 = oA.z; ob1 = oA.w;
                    oa2 = oB.x; ob2 = oB.y; oa3 = oB.z; ob3 = oB.w;
                    oa4 = oC.x; ob4 = oC.y;
                } else {
                    const int2* ip = (const int2*)(cidx + n * MAXNB);
                    int2 i0 = ip[0], i1 = ip[1], i2 = ip[2], i3 = ip[3], i4 = ip[4];
                    oa0 = i0.x << 3; ob0 = i0.y << 3;
                    oa1 = i1.x << 3; ob1 = i1.y << 3;
                    oa2 = i2.x << 3; ob2 = i2.y << 3;
                    oa3 = i3.x << 3; ob3 = i3.y << 3;
                    oa4 = i4.x << 3; ob4 = i4.y << 3;
                }
                v2f a0 = *(const v2f*)(smbase + oa0);
                v2f b0 = *(const v2f*)(smbase + ob0);
                v2f a1 = *(const v2f*)(smbase + oa1);
                v2f b1 = *(const v2f*)(smbase + ob1);
                v2f a2 = *(const v2f*)(smbase + oa2);
                v2f b2 = *(const v2f*)(smbase + ob2);
                v2f a3 = *(const v2f*)(smbase + oa3);
                v2f b3 = *(const v2f*)(smbase + ob3);
                v2f a4 = *(const v2f*)(smbase + oa4);
                v2f b4 = *(const v2f*)(smbase + ob4);
                // pk product tree: 9 packed muls
                v2f m01 = (a0 * b0) * (a1 * b1);
                v2f m23 = (a2 * b2) * (a3 * b3);
                v2f pr  = (m01 * m23) * (a4 * b4);
                pr = __builtin_elementwise_min(
                         __builtin_elementwise_max(pr, (v2f)(-0.999999f)),
                         (v2f)(0.999999f));
                v2f num = 1.0f + pr;                     // pk_add
                v2f den = 1.0f - pr;                     // pk_sub
                float check0 = 0.69314718f * (__log2f(num.x) - __log2f(den.x));
                float check1 = 0.69314718f * (__log2f(num.y) - __log2f(den.y));
                float wc, wr0, wr1;
                if (USE_OFF) {
                    float4 w = w4[n];
                    wc = w.x; wr0 = w.y; wr1 = w.z;
                } else {
                    wc = w_ch[n]; wr0 = w_res[n]; wr1 = w_res[NN + n];
                }
                float x0 = in0[n];
                float x1 = in1[n];
                float nv0 = fmaf(x0, wc, check0) + fmaf(wr0, vm0[k], wr1 * vmp0[k]);
                float nv1 = fmaf(x1, wc, check1) + fmaf(wr0, vm1[k], wr1 * vmp1[k]);
                vmp0[k] = vm0[k]; vm0[k] = nv0;
                vmp1[k] = vm1[k]; vm1[k] = nv1;
            }
        }
        __syncthreads();
    }

    // epilogue: sigmoid(vm + input)
    #pragma unroll
    for (int k = 0; k < MAXK; ++k) {
        int n = tid + k * TPB;
        if (k < MAXK - 1 || n < NN) {
            float x0 = vm0[k] + in0[n];
            float x1 = vm1[k] + in1[n];
            out0[n] = __fdividef(1.0f, 1.0f + __expf(-x0));
            out1[n] = __fdividef(1.0f, 1.0f + __expf(-x1));
        }
    }
}

extern "C" void kernel_launch(void* const* d_in, const int* in_sizes, int n_in,
                              void* d_out, int out_size, void* d_ws, size_t ws_size,
                              hipStream_t stream) {
    const float* input_llr = (const float*)d_in[0];
    const float* w_ch      = (const float*)d_in[1];
    const float* w_res     = (const float*)d_in[2];
    const int*   cidx      = (const int*)d_in[3];
    // d_in[4] (var_index_tensor) is unused by the reference
    float* out = (float*)d_out;
    int batch = in_sizes[0] / NN;
    const bool use_off = (ws_size >= WS_NEEDED) && (d_ws != nullptr);

    hipFuncSetAttribute((const void*)ldpc_decode_kernel<true>,
                        hipFuncAttributeMaxDynamicSharedMemorySize, LDS_BYTES);
    hipFuncSetAttribute((const void*)ldpc_decode_kernel<false>,
                        hipFuncAttributeMaxDynamicSharedMemorySize, LDS_BYTES);

    if (use_off) {
        int*    offs = (int*)d_ws;
        float4* w4   = (float4*)((char*)d_ws + OFFS_BYTES);
        hipLaunchKernelGGL(prep_kernel, dim3((NN + 255) / 256), dim3(256), 0,
                           stream, cidx, w_ch, w_res, offs, w4);
        hipLaunchKernelGGL(ldpc_decode_kernel<true>, dim3(batch / 2), dim3(TPB),
                           LDS_BYTES, stream, input_llr, w_ch, w_res, cidx,
                           offs, w4, out);
    } else {
        hipLaunchKernelGGL(ldpc_decode_kernel<false>, dim3(batch / 2), dim3(TPB),
                           LDS_BYTES, stream, input_llr, w_ch, w_res, cidx,
                           nullptr, nullptr, out);
    }
}